// Round 3
// baseline (134.795 us; speedup 1.0000x reference)
//
#include <hip/hip_runtime.h>
#include <hip/hip_fp16.h>

// Problem constants
#define N_VISITS  16384
#define MAX_CODES 64
#define DIM       64
#define NUM_CODES 100000
#define NRANGES   8
#define RANGE_SIZE 12500   // 8 * 12500 = 100000 exactly

typedef float f32x4 __attribute__((ext_vector_type(4)));

// ---------------------------------------------------------------------------
// Kernel A: convert emb table fp32 -> fp16 into workspace (12.8 MB).
// Streaming, HBM-bound (~7 us). nt reads (fp32 table used once); regular
// stores so the fp16 table lands warm in L2/L3 for the gather kernel.
// ---------------------------------------------------------------------------
__global__ __launch_bounds__(256) void emb_to_half_kernel(
    const float* __restrict__ emb, __half* __restrict__ embh)
{
    const size_t n8 = (size_t)NUM_CODES * DIM / 8;   // 800000 groups of 8 elems
    size_t i = (size_t)blockIdx.x * blockDim.x + threadIdx.x;
    const size_t stride = (size_t)gridDim.x * blockDim.x;
    for (; i < n8; i += stride) {
        const f32x4* src = (const f32x4*)emb + 2 * i;
        f32x4 a = __builtin_nontemporal_load(src);
        f32x4 b = __builtin_nontemporal_load(src + 1);
        union { __half2 h[4]; f32x4 f; } u;
        u.h[0] = __floats2half2_rn(a.x, a.y);
        u.h[1] = __floats2half2_rn(a.z, a.w);
        u.h[2] = __floats2half2_rn(b.x, b.y);
        u.h[3] = __floats2half2_rn(b.z, b.w);
        ((f32x4*)embh)[i] = u.f;
    }
}

// ---------------------------------------------------------------------------
// Kernel B: XCD-partitioned gather.
// Block b: id-range p = b&7 (12500 rows = 1.6 MB fp16 slice, fits a 4 MB
// per-XCD L2 since consecutive blocks round-robin XCDs), visit-group g = b>>3.
// One wave per visit. In-range ids (E ~ 8 of 64) are ballot-compacted into a
// per-wave LDS list; only ceil(nrows/8) wave-gathers issue (8 rows x 128 B
// each). Partial sums are pre-scaled by 1/count and nt-stored (256 B/visit).
// Correctness does NOT depend on the block->XCD mapping (coverage is by
// construction); only L2 locality does.
// ---------------------------------------------------------------------------
__global__ __launch_bounds__(256) void gather_partial_kernel(
    const int* __restrict__ code_ids,
    const __half* __restrict__ embh,
    float* __restrict__ partials)
{
    __shared__ int slots[4][64];

    const int w    = threadIdx.x >> 6;
    const int lane = threadIdx.x & 63;
    const int p    = blockIdx.x & 7;        // id-range == (intended) XCD
    const int g    = blockIdx.x >> 3;       // visit group
    const int visit = g * 4 + w;
    const int lo = p * RANGE_SIZE;
    const int hi = lo + RANGE_SIZE;

    const int r = lane >> 3;   // row slot within a gather instruction
    const int t = lane & 7;    // 16B chunk of the 128B row

    // ids are read by 8 range-blocks: nt keeps them out of L2 (L3 serves the
    // re-reads) so the table slice owns the L2.
    const int my_id = __builtin_nontemporal_load(
        code_ids + (size_t)visit * MAX_CODES + lane);

    const unsigned long long vmask = __ballot(my_id >= 0);
    const int total = __popcll(vmask);

    const bool inr = (my_id >= lo) && (my_id < hi);
    const unsigned long long rmask = __ballot(inr);
    const int nrows = __popcll(rmask);
    const int rank  = __popcll(rmask & ((1ull << lane) - 1ull));
    if (inr) slots[w][rank] = my_id;
    __syncthreads();   // cheap safety; all 256 threads reach this

    const int ngather = (nrows + 7) >> 3;

    float acc[8] = {0.f,0.f,0.f,0.f,0.f,0.f,0.f,0.f};
    for (int j = 0; j < ngather; ++j) {
        const int s = 8 * j + r;
        if (s < nrows) {                     // uniform per 8-lane row group
            const int id = slots[w][s];
            f32x4 v = *((const f32x4*)(embh + (size_t)id * DIM) + t);  // L2-local
            const __half2* h = (const __half2*)&v;
            #pragma unroll
            for (int k = 0; k < 4; ++k) {
                const float2 f = __half22float2(h[k]);
                acc[2 * k]     += f.x;
                acc[2 * k + 1] += f.y;
            }
        }
    }

    // Reduce the 8 row-slots (lane bits 3,4,5)
    #pragma unroll
    for (int k = 0; k < 8; ++k) acc[k] += __shfl_xor(acc[k], 8, 64);
    #pragma unroll
    for (int k = 0; k < 8; ++k) acc[k] += __shfl_xor(acc[k], 16, 64);
    #pragma unroll
    for (int k = 0; k < 8; ++k) acc[k] += __shfl_xor(acc[k], 32, 64);

    if (lane < 8) {
        const float scale = (total > 0) ? (1.0f / (float)total) : 0.0f;
        f32x4 o0, o1;
        o0.x = acc[0] * scale; o0.y = acc[1] * scale;
        o0.z = acc[2] * scale; o0.w = acc[3] * scale;
        o1.x = acc[4] * scale; o1.y = acc[5] * scale;
        o1.z = acc[6] * scale; o1.w = acc[7] * scale;
        f32x4* dst = (f32x4*)(partials + ((size_t)visit * NRANGES + p) * DIM + lane * 8);
        __builtin_nontemporal_store(o0, dst);       // nt: don't pollute L2
        __builtin_nontemporal_store(o1, dst + 1);
    }
}

// ---------------------------------------------------------------------------
// Kernel C: sum the 8 pre-scaled partials per visit -> out. Pure streaming
// (32 MB read, 4 MB write, ~6 us). One f32x4 (4 dims) per thread.
// ---------------------------------------------------------------------------
__global__ __launch_bounds__(256) void reduce_kernel(
    const float* __restrict__ partials, float* __restrict__ out)
{
    const int i = blockIdx.x * 256 + threadIdx.x;   // 262144 f32x4 chunks
    const int visit = i >> 4;                       // 16 chunks per visit
    const int c     = i & 15;                       // which 4-dim chunk

    const f32x4* base = (const f32x4*)partials + ((size_t)visit * NRANGES) * 16 + c;
    f32x4 s = __builtin_nontemporal_load(base);
    #pragma unroll
    for (int p = 1; p < NRANGES; ++p) {
        f32x4 v = __builtin_nontemporal_load(base + (size_t)p * 16);
        s.x += v.x; s.y += v.y; s.z += v.z; s.w += v.w;
    }
    __builtin_nontemporal_store(s, (f32x4*)out + i);
}

extern "C" void kernel_launch(void* const* d_in, const int* in_sizes, int n_in,
                              void* d_out, int out_size, void* d_ws, size_t ws_size,
                              hipStream_t stream) {
    const int*   code_ids = (const int*)d_in[0];    // [N_VISITS, MAX_CODES] int32
    const float* emb      = (const float*)d_in[1];  // [NUM_CODES, DIM] fp32
    float*       out      = (float*)d_out;          // [N_VISITS, DIM] fp32

    __half* embh     = (__half*)d_ws;                         // 12.8 MB
    float*  partials = (float*)((char*)d_ws + (16u << 20));   // 32 MB @ +16MB

    // A: fp32 -> fp16 table
    emb_to_half_kernel<<<2048, 256, 0, stream>>>(emb, embh);

    // B: partitioned gather -> per-(visit,range) scaled partials
    // grid = (16384/4 visits-per-block) * 8 ranges = 32768 blocks
    gather_partial_kernel<<<32768, 256, 0, stream>>>(code_ids, embh, partials);

    // C: reduce 8 partials -> out (262144 f32x4 chunks / 256 threads)
    reduce_kernel<<<1024, 256, 0, stream>>>(partials, out);
}

// Round 4
// 112.349 us; speedup vs baseline: 1.1998x; 1.1998x over previous
//
#include <hip/hip_runtime.h>
#include <hip/hip_fp16.h>

// Problem constants
#define N_VISITS  16384
#define MAX_CODES 64
#define DIM       64
#define NUM_CODES 100000
#define NRANGES   4
#define RANGE_SIZE 25000   // 4 * 25000 = 100000 exactly

typedef float f32x4 __attribute__((ext_vector_type(4)));

// ---------------------------------------------------------------------------
// Kernel A: convert emb table fp32 -> fp16 into workspace (12.8 MB).
// Streaming, HBM-bound (~6 us). nt reads (fp32 table used once); regular
// stores so the fp16 table lands warm in cache for the gather kernel.
// ---------------------------------------------------------------------------
__global__ __launch_bounds__(256) void emb_to_half_kernel(
    const float* __restrict__ emb, __half* __restrict__ embh)
{
    const size_t n8 = (size_t)NUM_CODES * DIM / 8;   // 800000 groups of 8 elems
    size_t i = (size_t)blockIdx.x * blockDim.x + threadIdx.x;
    const size_t stride = (size_t)gridDim.x * blockDim.x;
    for (; i < n8; i += stride) {
        const f32x4* src = (const f32x4*)emb + 2 * i;
        f32x4 a = __builtin_nontemporal_load(src);
        f32x4 b = __builtin_nontemporal_load(src + 1);
        union { __half2 h[4]; f32x4 f; } u;
        u.h[0] = __floats2half2_rn(a.x, a.y);
        u.h[1] = __floats2half2_rn(a.z, a.w);
        u.h[2] = __floats2half2_rn(b.x, b.y);
        u.h[3] = __floats2half2_rn(b.z, b.w);
        ((f32x4*)embh)[i] = u.f;
    }
}

// ---------------------------------------------------------------------------
// Kernel B: XCD-partitioned gather, LEAN version.
// Block b: range p = b&3 (25000 rows = 3.2 MB fp16 slice; consecutive blocks
// round-robin the 8 XCDs, and (b mod 8) mod 4 is constant per XCD, so each
// XCD's L2 serves exactly one slice). Visit group g = b>>2, one wave/visit.
// Lane layout: r = lane>>4 (4 row-slots), t = lane&15 (8B = 4 halfs of the
// 128B row). In-range ids (E ~ 16 of 64) are ballot-compacted into LDS
// (intra-wave, no barrier needed); ~4 gathers of 512B per wave follow.
// Accumulate fp32 (no mask needed - compacted ids are all valid), 8-shfl
// reduce, one 16B store per lane (16 lanes = 256B partial row, pre-scaled).
// Correctness does NOT depend on the block->XCD mapping, only locality does.
// ---------------------------------------------------------------------------
__global__ __launch_bounds__(256) void gather_partial_kernel(
    const int* __restrict__ code_ids,
    const __half* __restrict__ embh,
    float* __restrict__ partials)
{
    __shared__ int slots[4][64];

    const int w    = threadIdx.x >> 6;
    const int lane = threadIdx.x & 63;
    const int p    = blockIdx.x & 3;        // id-range (constant per XCD)
    const int g    = blockIdx.x >> 2;       // visit group
    const int visit = g * 4 + w;
    const int lo = p * RANGE_SIZE;
    const int hi = lo + RANGE_SIZE;

    const int r = lane >> 4;   // row slot within a gather instruction (0..3)
    const int t = lane & 15;   // 8B chunk of the 128B row (0..15)

    // ids are read by 4 range-blocks: nt keeps them out of L2 (L3 serves the
    // re-reads) so the table slice owns the L2.
    const int my_id = __builtin_nontemporal_load(
        code_ids + (size_t)visit * MAX_CODES + lane);

    const unsigned long long vmask = __ballot(my_id >= 0);
    const int total = __popcll(vmask);

    const bool inr = (my_id >= lo) && (my_id < hi);
    const unsigned long long rmask = __ballot(inr);
    const int nrows = __popcll(rmask);
    const int rank  = __popcll(rmask & ((1ull << lane) - 1ull));
    if (inr) slots[w][rank] = my_id;
    // Intra-wave LDS write->read: lockstep + lgkmcnt ordering, no barrier.

    const int ngather = (nrows + 3) >> 2;

    float acc[4] = {0.f, 0.f, 0.f, 0.f};
    for (int j = 0; j < ngather; ++j) {
        const int s = 4 * j + r;
        if (s < nrows) {                     // uniform per 16-lane row group
            const int id = slots[w][s];
            // 8B load: 4 halfs = dims 4t .. 4t+3 of row id. L2-local.
            const __half2* h = (const __half2*)(embh + (size_t)id * DIM + t * 4);
            const float2 f0 = __half22float2(h[0]);
            const float2 f1 = __half22float2(h[1]);
            acc[0] += f0.x; acc[1] += f0.y;
            acc[2] += f1.x; acc[3] += f1.y;
        }
    }

    // Reduce the 4 row-slots (lanes t, t+16, t+32, t+48): 2 stages x 4 floats
    #pragma unroll
    for (int k = 0; k < 4; ++k) acc[k] += __shfl_xor(acc[k], 16, 64);
    #pragma unroll
    for (int k = 0; k < 4; ++k) acc[k] += __shfl_xor(acc[k], 32, 64);

    if (lane < 16) {
        const float scale = (total > 0) ? (1.0f / (float)total) : 0.0f;
        f32x4 o;
        o.x = acc[0] * scale; o.y = acc[1] * scale;
        o.z = acc[2] * scale; o.w = acc[3] * scale;
        // 16 lanes x 16B = 256B pre-scaled partial row; nt: don't pollute L2.
        f32x4* dst = (f32x4*)(partials + ((size_t)visit * NRANGES + p) * DIM + t * 4);
        __builtin_nontemporal_store(o, dst);
    }
}

// ---------------------------------------------------------------------------
// Kernel C: sum the 4 pre-scaled partials per visit -> out. Pure streaming
// (16 MB read, 4 MB write, ~4 us). One f32x4 (4 dims) per thread.
// ---------------------------------------------------------------------------
__global__ __launch_bounds__(256) void reduce_kernel(
    const float* __restrict__ partials, float* __restrict__ out)
{
    const int i = blockIdx.x * 256 + threadIdx.x;   // 262144 f32x4 chunks
    const int visit = i >> 4;                       // 16 chunks per visit
    const int c     = i & 15;                       // which 4-dim chunk

    const f32x4* base = (const f32x4*)partials + ((size_t)visit * NRANGES) * 16 + c;
    f32x4 s = __builtin_nontemporal_load(base);
    #pragma unroll
    for (int p = 1; p < NRANGES; ++p) {
        f32x4 v = __builtin_nontemporal_load(base + (size_t)p * 16);
        s.x += v.x; s.y += v.y; s.z += v.z; s.w += v.w;
    }
    __builtin_nontemporal_store(s, (f32x4*)out + i);
}

extern "C" void kernel_launch(void* const* d_in, const int* in_sizes, int n_in,
                              void* d_out, int out_size, void* d_ws, size_t ws_size,
                              hipStream_t stream) {
    const int*   code_ids = (const int*)d_in[0];    // [N_VISITS, MAX_CODES] int32
    const float* emb      = (const float*)d_in[1];  // [NUM_CODES, DIM] fp32
    float*       out      = (float*)d_out;          // [N_VISITS, DIM] fp32

    __half* embh     = (__half*)d_ws;                         // 12.8 MB
    float*  partials = (float*)((char*)d_ws + (16u << 20));   // 16 MB @ +16MB

    // A: fp32 -> fp16 table
    emb_to_half_kernel<<<2048, 256, 0, stream>>>(emb, embh);

    // B: partitioned gather -> per-(visit,range) scaled partials
    // grid = (16384/4 visit groups) * 4 ranges = 16384 blocks
    gather_partial_kernel<<<16384, 256, 0, stream>>>(code_ids, embh, partials);

    // C: reduce 4 partials -> out (262144 f32x4 chunks / 256 threads)
    reduce_kernel<<<1024, 256, 0, stream>>>(partials, out);
}